// Round 3
// baseline (630.881 us; speedup 1.0000x reference)
//
#include <hip/hip_runtime.h>

// DIN attention unit, MI355X — round 3: fused layer-2 rank-1 updates to kill
// register spills (no h0d[32] array), CHUNKS 2->4 for occupancy.
//
// prep : wM[b][j][0..19], c[b][j] = fold(query, W0, b0)
// pass1: h0_pre -> per-channel sum/sumsq (32ch), channels split across waves
// fin0 : mean/var -> scale0/shift0
// pass2: h0_pre -> dice0 -> (fused) h1_pre -> sum/sumsq (16ch)
// fin1 : mean/var -> scale1/shift1
// pass3: full tower -> score -> out[b,:] += score * k
// mask input UNUSED (reference uses unmasked scores — reproduced bug).

#define BB 512
#define TT 2048
#define DD 20
#define C0 32
#define C1 16

#define NTH 256
#define CHUNKS 4
#define TCHUNK (TT / CHUNKS)  // 512
#define PPT (TCHUNK / NTH)    // 2 positions per thread

// ws float offsets
#define WS_SUM0 0
#define WS_SQ0 32
#define WS_SUM1 64
#define WS_SQ1 80
#define WS_SCALE0 96
#define WS_SHIFT0 128
#define WS_SCALE1 160
#define WS_SHIFT1 176
#define WS_BLOB 192
#define BLOB_J 24             // floats per channel row (20 wM + cj + pad)
#define BLOB_B (C0 * BLOB_J)  // 768 floats per batch

__device__ __forceinline__ float fast_sigmoid(float x) {
    return __builtin_amdgcn_rcpf(1.0f + __expf(-x));
}

__device__ __forceinline__ void load_krow(const float* __restrict__ row,
                                          float* kk) {
    const float4* kr = (const float4*)row;  // rows are 80B => 16B aligned
    float4 a = kr[0], b = kr[1], c = kr[2], d = kr[3], e = kr[4];
    kk[0] = a.x; kk[1] = a.y; kk[2] = a.z; kk[3] = a.w;
    kk[4] = b.x; kk[5] = b.y; kk[6] = b.z; kk[7] = b.w;
    kk[8] = c.x; kk[9] = c.y; kk[10] = c.z; kk[11] = c.w;
    kk[12] = d.x; kk[13] = d.y; kk[14] = d.z; kk[15] = d.w;
    kk[16] = e.x; kk[17] = e.y; kk[18] = e.z; kk[19] = e.w;
}

// ---------------- prep: fold query into layer-1 weights ----------------
__global__ void prep_kernel(const float* __restrict__ query,
                            const float* __restrict__ W0,
                            const float* __restrict__ b0,
                            float* __restrict__ blob) {
    const int b = blockIdx.x * 2 + (threadIdx.x >> 5);
    const int j = threadIdx.x & 31;
    float cj = b0[j];
    float* dst = blob + (size_t)b * BLOB_B + j * BLOB_J;
#pragma unroll
    for (int d = 0; d < DD; ++d) {
        float w_q = W0[d * C0 + j];
        float w_k = W0[(DD + d) * C0 + j];
        float w_d = W0[(2 * DD + d) * C0 + j];
        float w_p = W0[(3 * DD + d) * C0 + j];
        float qd = query[b * DD + d];
        dst[d] = w_k - w_d + qd * w_p;
        cj = fmaf(qd, w_q + w_d, cj);
    }
    dst[20] = cj;
}

// ---------------- pass 1: layer-1 pre-activation stats ----------------
// Channels split across waves (8 each): only 16 accumulators/thread.
__global__ __launch_bounds__(NTH) void pass1_kernel(
    const float* __restrict__ keys, const float* __restrict__ blob,
    float* __restrict__ sums) {
    const int b = blockIdx.x >> 2, chunk = blockIdx.x & 3;
    const int tid = threadIdx.x, wave = tid >> 6, lane = tid & 63;
    const int j0 = wave * 8;  // wave-uniform channel base
    const float* wb = blob + (size_t)b * BLOB_B;
    const float* kbase = keys + ((size_t)b * TT + chunk * TCHUNK) * DD;

    float s[8], q[8];
#pragma unroll
    for (int v = 0; v < 8; ++v) { s[v] = 0.f; q[v] = 0.f; }

#pragma unroll 1
    for (int it = 0; it < TCHUNK / 64; ++it) {
        float kk[DD];
        load_krow(kbase + (size_t)(it * 64 + lane) * DD, kk);
#pragma unroll
        for (int jj = 0; jj < 8; ++jj) {
            const float* w = wb + (j0 + jj) * BLOB_J;  // wave-uniform
            float h = w[20];
#pragma unroll
            for (int d = 0; d < DD; ++d) h = fmaf(kk[d], w[d], h);
            s[jj] += h;
            q[jj] = fmaf(h, h, q[jj]);
        }
    }
    float mine = 0.f;
#pragma unroll
    for (int v = 0; v < 16; ++v) {
        float val = (v < 8) ? s[v] : q[v - 8];
#pragma unroll
        for (int o = 32; o >= 1; o >>= 1) val += __shfl_xor(val, o);
        if (lane == v) mine = val;
    }
    __shared__ float red[64];
    if (lane < 16) {
        int j = j0 + (lane & 7);
        red[(lane < 8 ? 0 : 32) + j] = mine;  // distinct slots per wave
    }
    __syncthreads();
    if (tid < 64) atomicAdd(&sums[WS_SUM0 + tid], red[tid]);
}

// ---------------- finalize: mean/var -> scale/shift ----------------
__global__ void finalize_kernel(float* __restrict__ ws, int nch, int sumOff,
                                int sqOff, int scOff, int shOff) {
    int j = threadIdx.x;
    if (j < nch) {
        const float invN = 1.0f / (float)(BB * TT);
        float mean = ws[sumOff + j] * invN;
        float ex2 = ws[sqOff + j] * invN;
        float var = ex2 - mean * mean;
        float sc = rsqrtf(var + 1e-9f);
        ws[scOff + j] = sc;
        ws[shOff + j] = -mean * sc;
    }
}

// ---------------- pass 2: layer-2 pre-activation stats ----------------
// Fused: h0d_j is consumed immediately by a rank-1 update of h1[16].
__global__ __launch_bounds__(NTH) void pass2_kernel(
    const float* __restrict__ keys, const float* __restrict__ blob,
    const float* __restrict__ par, const float* __restrict__ a0,
    const float* __restrict__ W1, const float* __restrict__ b1,
    float* __restrict__ sums) {
    const int b = blockIdx.x >> 2, chunk = blockIdx.x & 3;
    const int tid = threadIdx.x, wave = tid >> 6, lane = tid & 63;
    const float* wb = blob + (size_t)b * BLOB_B;
    const float* kbase = keys + ((size_t)b * TT + chunk * TCHUNK) * DD;

    float s1[C1], q1[C1];
#pragma unroll
    for (int v = 0; v < C1; ++v) { s1[v] = 0.f; q1[v] = 0.f; }

#pragma unroll 1
    for (int it = 0; it < PPT; ++it) {
        float kk[DD];
        load_krow(kbase + (size_t)(it * NTH + tid) * DD, kk);
        float h1[C1];
#pragma unroll
        for (int jj = 0; jj < C1; ++jj) h1[jj] = b1[jj];
#pragma unroll
        for (int j = 0; j < C0; ++j) {
            const float* w = wb + j * BLOB_J;  // uniform -> s_load
            float h = w[20];
#pragma unroll
            for (int d = 0; d < DD; ++d) h = fmaf(kk[d], w[d], h);
            float p = fast_sigmoid(
                fmaf(h, par[WS_SCALE0 + j], par[WS_SHIFT0 + j]));
            float al = a0[j];
            float h0dj = h * (al + p * (1.0f - al));
            const float* wr = W1 + j * C1;  // uniform row -> s_load
#pragma unroll
            for (int jj = 0; jj < C1; ++jj)
                h1[jj] = fmaf(h0dj, wr[jj], h1[jj]);
        }
#pragma unroll
        for (int jj = 0; jj < C1; ++jj) {
            s1[jj] += h1[jj];
            q1[jj] = fmaf(h1[jj], h1[jj], q1[jj]);
        }
    }
    float mine = 0.f;
#pragma unroll
    for (int v = 0; v < 32; ++v) {
        float val = (v < C1) ? s1[v] : q1[v - C1];
#pragma unroll
        for (int o = 32; o >= 1; o >>= 1) val += __shfl_xor(val, o);
        if (lane == v) mine = val;
    }
    __shared__ float red[4][32];
    if (lane < 32) red[wave][lane] = mine;
    __syncthreads();
    if (tid < 32)
        atomicAdd(&sums[WS_SUM1 + tid],
                  red[0][tid] + red[1][tid] + red[2][tid] + red[3][tid]);
}

// ---------------- pass 3: full tower + weighted key-sum ----------------
__global__ __launch_bounds__(NTH) void pass3_kernel(
    const float* __restrict__ keys, const float* __restrict__ blob,
    const float* __restrict__ par, const float* __restrict__ a0,
    const float* __restrict__ W1, const float* __restrict__ b1,
    const float* __restrict__ a1, const float* __restrict__ wk,
    const float* __restrict__ bk, float* __restrict__ out) {
    const int b = blockIdx.x >> 2, chunk = blockIdx.x & 3;
    const int tid = threadIdx.x, lane = tid & 63;
    const float* wb = blob + (size_t)b * BLOB_B;
    const float* kbase = keys + ((size_t)b * TT + chunk * TCHUNK) * DD;

    float oacc[DD];
#pragma unroll
    for (int d = 0; d < DD; ++d) oacc[d] = 0.f;

#pragma unroll 1
    for (int it = 0; it < PPT; ++it) {
        float kk[DD];
        load_krow(kbase + (size_t)(it * NTH + tid) * DD, kk);
        float h1[C1];
#pragma unroll
        for (int jj = 0; jj < C1; ++jj) h1[jj] = b1[jj];
#pragma unroll
        for (int j = 0; j < C0; ++j) {
            const float* w = wb + j * BLOB_J;
            float h = w[20];
#pragma unroll
            for (int d = 0; d < DD; ++d) h = fmaf(kk[d], w[d], h);
            float p = fast_sigmoid(
                fmaf(h, par[WS_SCALE0 + j], par[WS_SHIFT0 + j]));
            float al = a0[j];
            float h0dj = h * (al + p * (1.0f - al));
            const float* wr = W1 + j * C1;
#pragma unroll
            for (int jj = 0; jj < C1; ++jj)
                h1[jj] = fmaf(h0dj, wr[jj], h1[jj]);
        }
        float score = bk[0];
#pragma unroll
        for (int jj = 0; jj < C1; ++jj) {
            float p = fast_sigmoid(
                fmaf(h1[jj], par[WS_SCALE1 + jj], par[WS_SHIFT1 + jj]));
            float al = a1[jj];
            float hd = h1[jj] * (al + p * (1.0f - al));
            score = fmaf(hd, wk[jj], score);
        }
#pragma unroll
        for (int d = 0; d < DD; ++d) oacc[d] = fmaf(score, kk[d], oacc[d]);
    }
    // wave butterfly per output dim; lane d keeps dim d; one atomic per wave
    float mine = 0.f;
#pragma unroll
    for (int d = 0; d < DD; ++d) {
        float val = oacc[d];
#pragma unroll
        for (int o = 32; o >= 1; o >>= 1) val += __shfl_xor(val, o);
        if (lane == d) mine = val;
    }
    if (lane < DD) atomicAdd(&out[b * DD + lane], mine);
}

extern "C" void kernel_launch(void* const* d_in, const int* in_sizes, int n_in,
                              void* d_out, int out_size, void* d_ws,
                              size_t ws_size, hipStream_t stream) {
    const float* keys = (const float*)d_in[0];
    const float* query = (const float*)d_in[1];
    // d_in[2] = mask: intentionally unused
    const float* W0 = (const float*)d_in[3];
    const float* b0 = (const float*)d_in[4];
    const float* a0 = (const float*)d_in[5];
    const float* W1 = (const float*)d_in[6];
    const float* b1 = (const float*)d_in[7];
    const float* a1 = (const float*)d_in[8];
    const float* wk = (const float*)d_in[9];
    const float* bk = (const float*)d_in[10];
    float* out = (float*)d_out;
    float* ws = (float*)d_ws;
    float* blob = ws + WS_BLOB;  // 512*768 floats = 1.5 MB of scratch

    hipMemsetAsync(ws, 0, 96 * sizeof(float), stream);  // sums area
    hipMemsetAsync(out, 0, (size_t)out_size * sizeof(float), stream);

    prep_kernel<<<BB / 2, 64, 0, stream>>>(query, W0, b0, blob);

    dim3 grid(BB * CHUNKS), blk(NTH);
    pass1_kernel<<<grid, blk, 0, stream>>>(keys, blob, ws);
    finalize_kernel<<<1, 32, 0, stream>>>(ws, 32, WS_SUM0, WS_SQ0, WS_SCALE0,
                                          WS_SHIFT0);
    pass2_kernel<<<grid, blk, 0, stream>>>(keys, blob, ws, a0, W1, b1, ws);
    finalize_kernel<<<1, 16, 0, stream>>>(ws, 16, WS_SUM1, WS_SQ1, WS_SCALE1,
                                          WS_SHIFT1);
    pass3_kernel<<<grid, blk, 0, stream>>>(keys, blob, ws, a0, W1, b1, a1, wk,
                                           bk, out);
}

// Round 4
// 523.158 us; speedup vs baseline: 1.2059x; 1.2059x over previous
//
#include <hip/hip_runtime.h>

// DIN attention unit, MI355X — round 4: register-resident weights.
// Pass2/3 use a hybrid lane map: 64 lanes = 16 positions x 4 channel-groups.
// Each lane holds 8 layer-1 channels' weights (~320 VGPR) loaded ONCE per
// block; the steady loop issues ZERO weight fetches (round-3 bottleneck:
// ~1300 s_loads per 64 positions re-fetching weights -> lgkmcnt stalls).
// Layer-2 partials combine via shfl reduce-scatter; each lane finishes with
// 4 layer-2 channels (keeps dice1 params at 20 VGPR/lane).
// mask input UNUSED (reference uses unmasked scores — reproduced bug).

#define BB 512
#define TT 2048
#define DD 20
#define C0 32
#define C1 16

// ws float offsets
#define WS_SUM0 0
#define WS_SQ0 32
#define WS_SUM1 64
#define WS_SQ1 80
#define WS_SCALE0 96
#define WS_SHIFT0 128
#define WS_SCALE1 160
#define WS_SHIFT1 176
#define WS_BLOB 192
#define BLOB_J 24             // floats per channel row (20 wM + cj + pad)
#define BLOB_B (C0 * BLOB_J)  // 768 floats per batch

__device__ __forceinline__ float fast_sigmoid(float x) {
    return __builtin_amdgcn_rcpf(1.0f + __expf(-x));
}

__device__ __forceinline__ void load_krow(const float* __restrict__ row,
                                          float* kk) {
    const float4* kr = (const float4*)row;  // rows are 80B => 16B aligned
    float4 a = kr[0], b = kr[1], c = kr[2], d = kr[3], e = kr[4];
    kk[0] = a.x; kk[1] = a.y; kk[2] = a.z; kk[3] = a.w;
    kk[4] = b.x; kk[5] = b.y; kk[6] = b.z; kk[7] = b.w;
    kk[8] = c.x; kk[9] = c.y; kk[10] = c.z; kk[11] = c.w;
    kk[12] = d.x; kk[13] = d.y; kk[14] = d.z; kk[15] = d.w;
    kk[16] = e.x; kk[17] = e.y; kk[18] = e.z; kk[19] = e.w;
}

// load one blob row (20 wM + c) into regs
__device__ __forceinline__ void load_wrow(const float* __restrict__ w,
                                          float* wM, float& cj) {
    load_krow(w, wM);
    cj = w[20];
}

// ---------------- prep: fold query into layer-1 weights ----------------
__global__ void prep_kernel(const float* __restrict__ query,
                            const float* __restrict__ W0,
                            const float* __restrict__ b0,
                            float* __restrict__ blob) {
    const int b = blockIdx.x * 2 + (threadIdx.x >> 5);
    const int j = threadIdx.x & 31;
    float cj = b0[j];
    float* dst = blob + (size_t)b * BLOB_B + j * BLOB_J;
#pragma unroll
    for (int d = 0; d < DD; ++d) {
        float w_q = W0[d * C0 + j];
        float w_k = W0[(DD + d) * C0 + j];
        float w_d = W0[(2 * DD + d) * C0 + j];
        float w_p = W0[(3 * DD + d) * C0 + j];
        float qd = query[b * DD + d];
        dst[d] = w_k - w_d + qd * w_p;
        cj = fmaf(qd, w_q + w_d, cj);
    }
    dst[20] = cj;
}

// ---------------- pass 1: layer-1 pre-activation stats ----------------
// 8 channels per wave, weights hoisted to VGPRs (no per-position refetch).
__global__ __launch_bounds__(256, 2) void pass1_kernel(
    const float* __restrict__ keys, const float* __restrict__ blob,
    float* __restrict__ ws) {
    const int b = blockIdx.x >> 2, chunk = blockIdx.x & 3;
    const int tid = threadIdx.x, wave = tid >> 6, lane = tid & 63;
    const int j0 = wave * 8;
    const float* wb = blob + (size_t)b * BLOB_B;
    const float* kbase = keys + ((size_t)b * TT + chunk * (TT / 4)) * DD;

    float wM[8][DD], cj8[8];
#pragma unroll
    for (int jj = 0; jj < 8; ++jj)
        load_wrow(wb + (j0 + jj) * BLOB_J, wM[jj], cj8[jj]);

    float s[8], q[8];
#pragma unroll
    for (int v = 0; v < 8; ++v) { s[v] = 0.f; q[v] = 0.f; }

#pragma unroll 1
    for (int it = 0; it < (TT / 4) / 64; ++it) {
        float kk[DD];
        load_krow(kbase + (size_t)(it * 64 + lane) * DD, kk);
#pragma unroll
        for (int jj = 0; jj < 8; ++jj) {
            float h = cj8[jj];
#pragma unroll
            for (int d = 0; d < DD; ++d) h = fmaf(kk[d], wM[jj][d], h);
            s[jj] += h;
            q[jj] = fmaf(h, h, q[jj]);
        }
    }
    float mine = 0.f;
#pragma unroll
    for (int v = 0; v < 16; ++v) {
        float val = (v < 8) ? s[v] : q[v - 8];
#pragma unroll
        for (int o = 32; o >= 1; o >>= 1) val += __shfl_xor(val, o);
        if (lane == v) mine = val;
    }
    __shared__ float red[64];
    if (lane < 16) {
        int j = j0 + (lane & 7);
        red[(lane < 8 ? 0 : 32) + j] = mine;
    }
    __syncthreads();
    if (tid < 64) atomicAdd(&ws[WS_SUM0 + tid], red[tid]);
}

// ---------------- finalize: mean/var -> scale/shift ----------------
__global__ void finalize_kernel(float* __restrict__ ws, int nch, int sumOff,
                                int sqOff, int scOff, int shOff) {
    int j = threadIdx.x;
    if (j < nch) {
        const float invN = 1.0f / (float)(BB * TT);
        float mean = ws[sumOff + j] * invN;
        float ex2 = ws[sqOff + j] * invN;
        float var = ex2 - mean * mean;
        float sc = rsqrtf(var + 1e-9f);
        ws[scOff + j] = sc;
        ws[shOff + j] = -mean * sc;
    }
}

// Shared tower prologue for pass2/pass3: per-lane weight residency.
// lane = p (position 0..15) + 16*g (channel-group 0..3); lane's layer-1
// channels are j = g + 4*jj, jj=0..7; lane's layer-2 channels are 4g..4g+3.
#define TOWER_PREAMBLE()                                                     \
    const int b = blockIdx.x >> 1, chunk = blockIdx.x & 1;                   \
    const int lane = threadIdx.x;                                            \
    const int p = lane & 15, g = lane >> 4;                                  \
    const float* wb = blob + (size_t)b * BLOB_B;                             \
    const float* kbase = keys + ((size_t)b * TT + chunk * (TT / 2)) * DD;    \
    float wM[8][DD], cj8[8], sc0v[8], sh0v[8], al0v[8], w1r[8][C1];          \
    _Pragma("unroll") for (int jj = 0; jj < 8; ++jj) {                       \
        int j = g + 4 * jj;                                                  \
        load_wrow(wb + j * BLOB_J, wM[jj], cj8[jj]);                         \
        sc0v[jj] = ws[WS_SCALE0 + j];                                        \
        sh0v[jj] = ws[WS_SHIFT0 + j];                                        \
        al0v[jj] = a0[j];                                                    \
        const float4* w14 = (const float4*)(W1 + j * C1);                    \
        float4 A = w14[0], B = w14[1], C = w14[2], E = w14[3];               \
        w1r[jj][0] = A.x;  w1r[jj][1] = A.y;  w1r[jj][2] = A.z;              \
        w1r[jj][3] = A.w;  w1r[jj][4] = B.x;  w1r[jj][5] = B.y;              \
        w1r[jj][6] = B.z;  w1r[jj][7] = B.w;  w1r[jj][8] = C.x;              \
        w1r[jj][9] = C.y;  w1r[jj][10] = C.z; w1r[jj][11] = C.w;             \
        w1r[jj][12] = E.x; w1r[jj][13] = E.y; w1r[jj][14] = E.z;             \
        w1r[jj][15] = E.w;                                                   \
    }                                                                        \
    float b1v[4];                                                            \
    _Pragma("unroll") for (int i = 0; i < 4; ++i) b1v[i] = b1[4 * g + i];

// Body producing r4[4] = this lane's 4 layer-2 pre-activations (+b1) for
// position (it*16+p). kk[] left holding the key row.
#define TOWER_BODY(it)                                                       \
    float kk[DD];                                                            \
    load_krow(kbase + (size_t)((it)*16 + p) * DD, kk);                       \
    float p1[C1];                                                            \
    _Pragma("unroll") for (int c = 0; c < C1; ++c) p1[c] = 0.f;              \
    _Pragma("unroll") for (int jj = 0; jj < 8; ++jj) {                       \
        float h = cj8[jj];                                                   \
        _Pragma("unroll") for (int d = 0; d < DD; ++d)                       \
            h = fmaf(kk[d], wM[jj][d], h);                                   \
        float pr = fast_sigmoid(fmaf(h, sc0v[jj], sh0v[jj]));                \
        float al = al0v[jj];                                                 \
        float h0dj = h * (al + pr * (1.0f - al));                            \
        _Pragma("unroll") for (int c = 0; c < C1; ++c)                       \
            p1[c] = fmaf(h0dj, w1r[jj][c], p1[c]);                           \
    }                                                                        \
    /* reduce-scatter across 4 channel-groups (xor32 -> sel -> xor16 -> sel) */ \
    _Pragma("unroll") for (int c = 0; c < C1; ++c)                           \
        p1[c] += __shfl_xor(p1[c], 32);                                      \
    float q8[8];                                                             \
    _Pragma("unroll") for (int c = 0; c < 8; ++c)                            \
        q8[c] = (g & 2) ? p1[c + 8] : p1[c];                                 \
    _Pragma("unroll") for (int c = 0; c < 8; ++c)                            \
        q8[c] += __shfl_xor(q8[c], 16);                                      \
    float r4[4];                                                             \
    _Pragma("unroll") for (int i = 0; i < 4; ++i)                            \
        r4[i] = ((g & 1) ? q8[i + 4] : q8[i]) + b1v[i];

// ---------------- pass 2: layer-2 pre-activation stats ----------------
__global__ __launch_bounds__(64, 1) void pass2_kernel(
    const float* __restrict__ keys, const float* __restrict__ blob,
    const float* __restrict__ a0, const float* __restrict__ W1,
    const float* __restrict__ b1, float* ws) {
    TOWER_PREAMBLE()

    float s1v[4] = {0.f, 0.f, 0.f, 0.f}, q1v[4] = {0.f, 0.f, 0.f, 0.f};

#pragma unroll 1
    for (int it = 0; it < (TT / 2) / 16; ++it) {
        TOWER_BODY(it)
        (void)kk;
#pragma unroll
        for (int i = 0; i < 4; ++i) {
            s1v[i] += r4[i];
            q1v[i] = fmaf(r4[i], r4[i], q1v[i]);
        }
    }
    // sum over the 16 position-lanes
#pragma unroll
    for (int i = 0; i < 4; ++i) {
#pragma unroll
        for (int m = 1; m <= 8; m <<= 1) {
            s1v[i] += __shfl_xor(s1v[i], m);
            q1v[i] += __shfl_xor(q1v[i], m);
        }
    }
    if (p == 0) {
#pragma unroll
        for (int i = 0; i < 4; ++i) {
            atomicAdd(&ws[WS_SUM1 + 4 * g + i], s1v[i]);
            atomicAdd(&ws[WS_SQ1 + 4 * g + i], q1v[i]);
        }
    }
}

// ---------------- pass 3: full tower + weighted key-sum ----------------
__global__ __launch_bounds__(64, 1) void pass3_kernel(
    const float* __restrict__ keys, const float* __restrict__ blob,
    const float* __restrict__ a0, const float* __restrict__ W1,
    const float* __restrict__ b1, const float* __restrict__ a1,
    const float* __restrict__ wk, const float* __restrict__ bk, float* ws,
    float* __restrict__ out) {
    TOWER_PREAMBLE()

    float sc1v[4], sh1v[4], al1v[4], wkv[4];
#pragma unroll
    for (int i = 0; i < 4; ++i) {
        int c = 4 * g + i;
        sc1v[i] = ws[WS_SCALE1 + c];
        sh1v[i] = ws[WS_SHIFT1 + c];
        al1v[i] = a1[c];
        wkv[i] = wk[c];
    }
    const float bkv = bk[0];

    float oacc[DD];
#pragma unroll
    for (int d = 0; d < DD; ++d) oacc[d] = 0.f;

#pragma unroll 1
    for (int it = 0; it < (TT / 2) / 16; ++it) {
        TOWER_BODY(it)
        float sp = 0.f;
#pragma unroll
        for (int i = 0; i < 4; ++i) {
            float pr = fast_sigmoid(fmaf(r4[i], sc1v[i], sh1v[i]));
            float al = al1v[i];
            float hd = r4[i] * (al + pr * (1.0f - al));
            sp = fmaf(hd, wkv[i], sp);
        }
        sp += __shfl_xor(sp, 16);
        sp += __shfl_xor(sp, 32);
        float score = sp + bkv;
#pragma unroll
        for (int d = 0; d < DD; ++d) oacc[d] = fmaf(score, kk[d], oacc[d]);
    }
    // 64-lane reduce; each position was accumulated by 4 lanes -> x0.25
    float mine = 0.f;
#pragma unroll
    for (int v = 0; v < DD; ++v) {
        float val = oacc[v];
#pragma unroll
        for (int o = 32; o >= 1; o >>= 1) val += __shfl_xor(val, o);
        if (lane == v) mine = val * 0.25f;
    }
    if (lane < DD) atomicAdd(&out[b * DD + lane], mine);
}

extern "C" void kernel_launch(void* const* d_in, const int* in_sizes, int n_in,
                              void* d_out, int out_size, void* d_ws,
                              size_t ws_size, hipStream_t stream) {
    const float* keys = (const float*)d_in[0];
    const float* query = (const float*)d_in[1];
    // d_in[2] = mask: intentionally unused
    const float* W0 = (const float*)d_in[3];
    const float* b0 = (const float*)d_in[4];
    const float* a0 = (const float*)d_in[5];
    const float* W1 = (const float*)d_in[6];
    const float* b1 = (const float*)d_in[7];
    const float* a1 = (const float*)d_in[8];
    const float* wk = (const float*)d_in[9];
    const float* bk = (const float*)d_in[10];
    float* out = (float*)d_out;
    float* ws = (float*)d_ws;
    float* blob = ws + WS_BLOB;  // 512*768 floats = 1.5 MB of scratch

    hipMemsetAsync(ws, 0, 96 * sizeof(float), stream);  // sums area
    hipMemsetAsync(out, 0, (size_t)out_size * sizeof(float), stream);

    prep_kernel<<<BB / 2, 64, 0, stream>>>(query, W0, b0, blob);

    pass1_kernel<<<BB * 4, 256, 0, stream>>>(keys, blob, ws);
    finalize_kernel<<<1, 32, 0, stream>>>(ws, 32, WS_SUM0, WS_SQ0, WS_SCALE0,
                                          WS_SHIFT0);
    pass2_kernel<<<BB * 2, 64, 0, stream>>>(keys, blob, a0, W1, b1, ws);
    finalize_kernel<<<1, 16, 0, stream>>>(ws, 16, WS_SUM1, WS_SQ1, WS_SCALE1,
                                          WS_SHIFT1);
    pass3_kernel<<<BB * 2, 64, 0, stream>>>(keys, blob, a0, W1, b1, a1, wk, bk,
                                            ws, out);
}

// Round 5
// 320.544 us; speedup vs baseline: 1.9682x; 1.6321x over previous
//
#include <hip/hip_runtime.h>

// DIN attention unit, MI355X — round 5: position-per-thread + 4-position
// register blocking + LDS-staged weights read at wave-uniform addresses
// (broadcast, conflict-free). No cross-lane ops in the main work; the only
// reduction is one butterfly at thread end. Fixes R4 (shfl storm, 1 wave/SIMD)
// and R3 (per-position weight re-fetch).
// mask input UNUSED (reference uses unmasked scores — reproduced bug).

#define BB 512
#define TT 2048
#define DD 20
#define C0 32
#define C1 16

#define NTH 128            // 2 waves/block
#define NPOS 4             // positions per thread (register-blocked)
#define POSB (NTH * NPOS)  // 512 positions per block
#define NBLK (TT / POSB)   // 4 blocks per batch

// ws float offsets
#define WS_SUM0 0
#define WS_SQ0 32
#define WS_SUM1 64
#define WS_SQ1 80
#define WS_SCALE0 96
#define WS_SHIFT0 128
#define WS_SCALE1 160
#define WS_SHIFT1 176
#define WS_BLOB 192
#define BLOB_J 24             // 20 wM + c + pad
#define BLOB_B (C0 * BLOB_J)  // 768 floats per batch

__device__ __forceinline__ float fast_sigmoid(float x) {
    return __builtin_amdgcn_rcpf(1.0f + __expf(-x));
}

__device__ __forceinline__ void load_krow(const float* __restrict__ row,
                                          float* kk) {
    const float4* kr = (const float4*)row;  // rows are 80B => 16B aligned
    float4 a = kr[0], b = kr[1], c = kr[2], d = kr[3], e = kr[4];
    kk[0] = a.x; kk[1] = a.y; kk[2] = a.z; kk[3] = a.w;
    kk[4] = b.x; kk[5] = b.y; kk[6] = b.z; kk[7] = b.w;
    kk[8] = c.x; kk[9] = c.y; kk[10] = c.z; kk[11] = c.w;
    kk[12] = d.x; kk[13] = d.y; kk[14] = d.z; kk[15] = d.w;
    kk[16] = e.x; kk[17] = e.y; kk[18] = e.z; kk[19] = e.w;
}

// ---------------- prep: fold query into layer-1 weights ----------------
__global__ void prep_kernel(const float* __restrict__ query,
                            const float* __restrict__ W0,
                            const float* __restrict__ b0,
                            float* __restrict__ blob) {
    const int b = blockIdx.x * 2 + (threadIdx.x >> 5);
    const int j = threadIdx.x & 31;
    float cj = b0[j];
    float* dst = blob + (size_t)b * BLOB_B + j * BLOB_J;
#pragma unroll
    for (int d = 0; d < DD; ++d) {
        float w_q = W0[d * C0 + j];
        float w_k = W0[(DD + d) * C0 + j];
        float w_d = W0[(2 * DD + d) * C0 + j];
        float w_p = W0[(3 * DD + d) * C0 + j];
        float qd = query[b * DD + d];
        dst[d] = w_k - w_d + qd * w_p;
        cj = fmaf(qd, w_q + w_d, cj);
    }
    dst[20] = cj;
}

// ---------------- pass 1: layer-1 pre-activation stats ----------------
// 8 channels per wave, weights VGPR-resident, 64 positions per iteration.
__global__ __launch_bounds__(256, 2) void pass1_kernel(
    const float* __restrict__ keys, const float* __restrict__ blob,
    float* __restrict__ ws) {
    const int b = blockIdx.x >> 2, chunk = blockIdx.x & 3;
    const int tid = threadIdx.x, wave = tid >> 6, lane = tid & 63;
    const int j0 = wave * 8;
    const float* wb = blob + (size_t)b * BLOB_B;
    const float* kbase = keys + ((size_t)b * TT + chunk * (TT / 4)) * DD;

    float wM[8][DD], cj8[8];
#pragma unroll
    for (int jj = 0; jj < 8; ++jj) {
        load_krow(wb + (j0 + jj) * BLOB_J, wM[jj]);
        cj8[jj] = wb[(j0 + jj) * BLOB_J + 20];
    }

    float s[8], q[8];
#pragma unroll
    for (int v = 0; v < 8; ++v) { s[v] = 0.f; q[v] = 0.f; }

#pragma unroll 1
    for (int it = 0; it < (TT / 4) / 64; ++it) {
        float kk[DD];
        load_krow(kbase + (size_t)(it * 64 + lane) * DD, kk);
#pragma unroll
        for (int jj = 0; jj < 8; ++jj) {
            float h = cj8[jj];
#pragma unroll
            for (int d = 0; d < DD; ++d) h = fmaf(kk[d], wM[jj][d], h);
            s[jj] += h;
            q[jj] = fmaf(h, h, q[jj]);
        }
    }
    float mine = 0.f;
#pragma unroll
    for (int v = 0; v < 16; ++v) {
        float val = (v < 8) ? s[v] : q[v - 8];
#pragma unroll
        for (int o = 32; o >= 1; o >>= 1) val += __shfl_xor(val, o);
        if (lane == v) mine = val;
    }
    __shared__ float red[64];
    if (lane < 16) {
        int j = j0 + (lane & 7);
        red[(lane < 8 ? 0 : 32) + j] = mine;
    }
    __syncthreads();
    if (tid < 64) atomicAdd(&ws[WS_SUM0 + tid], red[tid]);
}

// ---------------- finalize: mean/var -> scale/shift ----------------
__global__ void finalize_kernel(float* __restrict__ ws, int nch, int sumOff,
                                int sqOff, int scOff, int shOff) {
    int j = threadIdx.x;
    if (j < nch) {
        const float invN = 1.0f / (float)(BB * TT);
        float mean = ws[sumOff + j] * invN;
        float ex2 = ws[sqOff + j] * invN;
        float var = ex2 - mean * mean;
        float sc = rsqrtf(var + 1e-9f);
        ws[scOff + j] = sc;
        ws[shOff + j] = -mean * sc;
    }
}

// Stage per-batch weights into LDS (wave-uniform broadcast reads in loop).
// lw[j*24]: [0..19]=wM, [20]=c, [21]=sc0, [22]=sh0, [23]=al0. lw1: W1 rows.
#define STAGE_WEIGHTS()                                                      \
    for (int idx = tid; idx < C0 * 24; idx += NTH) {                         \
        int j = idx / 24, r = idx - j * 24;                                  \
        float v;                                                             \
        if (r < 21) v = blob[(size_t)b * BLOB_B + j * BLOB_J + r];           \
        else if (r == 21) v = ws[WS_SCALE0 + j];                             \
        else if (r == 22) v = ws[WS_SHIFT0 + j];                             \
        else v = a0[j];                                                      \
        lw[idx] = v;                                                         \
    }                                                                        \
    for (int idx = tid; idx < C0 * C1; idx += NTH) lw1[idx] = W1[idx];

// j-loop: per channel, broadcast-load 24+16 weight floats from LDS, apply to
// NPOS positions. h1[pp][c] accumulates layer-2 pre-activations (minus b1).
#define TOWER_JLOOP()                                                        \
    _Pragma("unroll 2") for (int j = 0; j < C0; ++j) {                       \
        const float* w = &lw[j * 24];                                        \
        float h[NPOS];                                                       \
        _Pragma("unroll") for (int pp = 0; pp < NPOS; ++pp) {                \
            float hh = w[20];                                                \
            _Pragma("unroll") for (int d = 0; d < DD; ++d)                   \
                hh = fmaf(kk[pp][d], w[d], hh);                              \
            h[pp] = hh;                                                      \
        }                                                                    \
        const float sc = w[21], sh = w[22], al = w[23];                      \
        const float* w1r = &lw1[j * C1];                                     \
        _Pragma("unroll") for (int pp = 0; pp < NPOS; ++pp) {                \
            float pr = fast_sigmoid(fmaf(h[pp], sc, sh));                    \
            float h0d = h[pp] * (al + pr * (1.0f - al));                     \
            _Pragma("unroll") for (int c = 0; c < C1; ++c)                   \
                h1[pp][c] = fmaf(h0d, w1r[c], h1[pp][c]);                    \
        }                                                                    \
    }

// ---------------- pass 2: layer-2 pre-activation stats ----------------
__global__ __launch_bounds__(NTH, 2) void pass2_kernel(
    const float* __restrict__ keys, const float* __restrict__ blob,
    const float* __restrict__ a0, const float* __restrict__ W1,
    const float* __restrict__ b1, float* __restrict__ ws) {
    const int b = blockIdx.x >> 2, chunk = blockIdx.x & 3;
    const int tid = threadIdx.x, wave = tid >> 6, lane = tid & 63;
    __shared__ float lw[C0 * 24];
    __shared__ float lw1[C0 * C1];
    __shared__ float red[2][32];
    STAGE_WEIGHTS()
    __syncthreads();

    const float* kbase = keys + ((size_t)b * TT + chunk * POSB) * DD;
    float kk[NPOS][DD];
#pragma unroll
    for (int pp = 0; pp < NPOS; ++pp)
        load_krow(kbase + (size_t)(tid + pp * NTH) * DD, kk[pp]);

    float h1[NPOS][C1];
#pragma unroll
    for (int pp = 0; pp < NPOS; ++pp)
#pragma unroll
        for (int c = 0; c < C1; ++c) h1[pp][c] = 0.f;

    TOWER_JLOOP()

    // add b1 (uniform s_load), accumulate thread-local stats
    float s1[C1], q1[C1];
#pragma unroll
    for (int c = 0; c < C1; ++c) {
        float bc = b1[c], sv = 0.f, qv = 0.f;
#pragma unroll
        for (int pp = 0; pp < NPOS; ++pp) {
            float v = h1[pp][c] + bc;
            sv += v;
            qv = fmaf(v, v, qv);
        }
        s1[c] = sv;
        q1[c] = qv;
    }
    // one butterfly at the very end
    float mine = 0.f;
#pragma unroll
    for (int v = 0; v < 32; ++v) {
        float val = (v < C1) ? s1[v] : q1[v - C1];
#pragma unroll
        for (int o = 32; o >= 1; o >>= 1) val += __shfl_xor(val, o);
        if (lane == v) mine = val;
    }
    if (lane < 32) red[wave][lane] = mine;
    __syncthreads();
    if (tid < 32) atomicAdd(&ws[WS_SUM1 + tid], red[0][tid] + red[1][tid]);
}

// ---------------- pass 3: full tower + weighted key-sum ----------------
__global__ __launch_bounds__(NTH, 2) void pass3_kernel(
    const float* __restrict__ keys, const float* __restrict__ blob,
    const float* __restrict__ a0, const float* __restrict__ W1,
    const float* __restrict__ b1, const float* __restrict__ a1,
    const float* __restrict__ wk, const float* __restrict__ bk,
    const float* __restrict__ ws, float* __restrict__ out) {
    const int b = blockIdx.x >> 2, chunk = blockIdx.x & 3;
    const int tid = threadIdx.x, wave = tid >> 6, lane = tid & 63;
    __shared__ float lw[C0 * 24];
    __shared__ float lw1[C0 * C1];
    __shared__ float ld1[C1 * 4];  // sc1, sh1, al1, wk per layer-2 channel
    __shared__ float red[2][DD];
    STAGE_WEIGHTS()
    if (tid < C1) {
        ld1[tid * 4 + 0] = ws[WS_SCALE1 + tid];
        ld1[tid * 4 + 1] = ws[WS_SHIFT1 + tid];
        ld1[tid * 4 + 2] = a1[tid];
        ld1[tid * 4 + 3] = wk[tid];
    }
    __syncthreads();

    const float* kbase = keys + ((size_t)b * TT + chunk * POSB) * DD;
    float kk[NPOS][DD];
#pragma unroll
    for (int pp = 0; pp < NPOS; ++pp)
        load_krow(kbase + (size_t)(tid + pp * NTH) * DD, kk[pp]);

    float h1[NPOS][C1];
#pragma unroll
    for (int pp = 0; pp < NPOS; ++pp)
#pragma unroll
        for (int c = 0; c < C1; ++c) h1[pp][c] = 0.f;

    TOWER_JLOOP()

    // thread-local dice1 + score + weighted-key accumulation
    const float bkv = bk[0];
    float oacc[DD];
#pragma unroll
    for (int d = 0; d < DD; ++d) oacc[d] = 0.f;
#pragma unroll
    for (int pp = 0; pp < NPOS; ++pp) {
        float score = bkv;
#pragma unroll
        for (int c = 0; c < C1; ++c) {
            float v = h1[pp][c] + b1[c];
            float pr = fast_sigmoid(fmaf(v, ld1[c * 4 + 0], ld1[c * 4 + 1]));
            float al = ld1[c * 4 + 2];
            float hd = v * (al + pr * (1.0f - al));
            score = fmaf(hd, ld1[c * 4 + 3], score);
        }
#pragma unroll
        for (int d = 0; d < DD; ++d) oacc[d] = fmaf(score, kk[pp][d], oacc[d]);
    }
    // one butterfly at the very end
    float mine = 0.f;
#pragma unroll
    for (int v = 0; v < DD; ++v) {
        float val = oacc[v];
#pragma unroll
        for (int o = 32; o >= 1; o >>= 1) val += __shfl_xor(val, o);
        if (lane == v) mine = val;
    }
    if (lane < DD) red[wave][lane] = mine;
    __syncthreads();
    if (tid < DD) atomicAdd(&out[b * DD + tid], red[0][tid] + red[1][tid]);
}

extern "C" void kernel_launch(void* const* d_in, const int* in_sizes, int n_in,
                              void* d_out, int out_size, void* d_ws,
                              size_t ws_size, hipStream_t stream) {
    const float* keys = (const float*)d_in[0];
    const float* query = (const float*)d_in[1];
    // d_in[2] = mask: intentionally unused
    const float* W0 = (const float*)d_in[3];
    const float* b0 = (const float*)d_in[4];
    const float* a0 = (const float*)d_in[5];
    const float* W1 = (const float*)d_in[6];
    const float* b1 = (const float*)d_in[7];
    const float* a1 = (const float*)d_in[8];
    const float* wk = (const float*)d_in[9];
    const float* bk = (const float*)d_in[10];
    float* out = (float*)d_out;
    float* ws = (float*)d_ws;
    float* blob = ws + WS_BLOB;  // 512*768 floats = 1.5 MB scratch

    hipMemsetAsync(ws, 0, 96 * sizeof(float), stream);  // sums area
    hipMemsetAsync(out, 0, (size_t)out_size * sizeof(float), stream);

    prep_kernel<<<BB / 2, 64, 0, stream>>>(query, W0, b0, blob);

    pass1_kernel<<<BB * 4, 256, 0, stream>>>(keys, blob, ws);
    finalize_kernel<<<1, 32, 0, stream>>>(ws, 32, WS_SUM0, WS_SQ0, WS_SCALE0,
                                          WS_SHIFT0);
    pass2_kernel<<<BB * NBLK, NTH, 0, stream>>>(keys, blob, a0, W1, b1, ws);
    finalize_kernel<<<1, 16, 0, stream>>>(ws, 16, WS_SUM1, WS_SQ1, WS_SCALE1,
                                          WS_SHIFT1);
    pass3_kernel<<<BB * NBLK, NTH, 0, stream>>>(keys, blob, a0, W1, b1, a1, wk,
                                                bk, ws, out);
}

// Round 6
// 288.827 us; speedup vs baseline: 2.1843x; 1.1098x over previous
//
#include <hip/hip_runtime.h>

// DIN attention unit, MI355X — round 6: R5 structure + VGPR pinning.
// R5 diagnosis: VGPR_Count=84 proved the compiler rematerialized (re-loaded)
// the key rows inside the j-loop instead of keeping kk[4][20] resident ->
// per-j vmcnt stalls. Fix: empty inline-asm "+v" constraints pin kk (and
// pass1's wM) in VGPRs; explicit float4 LDS reads guarantee ds_read_b128.
// mask input UNUSED (reference uses unmasked scores — reproduced bug).

#define BB 512
#define TT 2048
#define DD 20
#define C0 32
#define C1 16

#define NTH 256            // 4 waves/block
#define NPOS 4             // positions per thread (register-blocked)
#define POSB (NTH * NPOS)  // 1024 positions per block
#define NBLK (TT / POSB)   // 2 blocks per batch

// ws float offsets
#define WS_SUM0 0
#define WS_SQ0 32
#define WS_SUM1 64
#define WS_SQ1 80
#define WS_SCALE0 96
#define WS_SHIFT0 128
#define WS_SCALE1 160
#define WS_SHIFT1 176
#define WS_BLOB 192
#define BLOB_J 24             // 20 wM + c + pad
#define BLOB_B (C0 * BLOB_J)  // 768 floats per batch

#define PIN(x) asm volatile("" : "+v"(x))

__device__ __forceinline__ float fast_sigmoid(float x) {
    return __builtin_amdgcn_rcpf(1.0f + __expf(-x));
}

__device__ __forceinline__ void load_krow(const float* __restrict__ row,
                                          float* kk) {
    const float4* kr = (const float4*)row;  // rows are 80B => 16B aligned
    float4 a = kr[0], b = kr[1], c = kr[2], d = kr[3], e = kr[4];
    kk[0] = a.x; kk[1] = a.y; kk[2] = a.z; kk[3] = a.w;
    kk[4] = b.x; kk[5] = b.y; kk[6] = b.z; kk[7] = b.w;
    kk[8] = c.x; kk[9] = c.y; kk[10] = c.z; kk[11] = c.w;
    kk[12] = d.x; kk[13] = d.y; kk[14] = d.z; kk[15] = d.w;
    kk[16] = e.x; kk[17] = e.y; kk[18] = e.z; kk[19] = e.w;
}

// ---------------- prep: fold query into layer-1 weights ----------------
__global__ void prep_kernel(const float* __restrict__ query,
                            const float* __restrict__ W0,
                            const float* __restrict__ b0,
                            float* __restrict__ blob) {
    const int b = blockIdx.x * 2 + (threadIdx.x >> 5);
    const int j = threadIdx.x & 31;
    float cj = b0[j];
    float* dst = blob + (size_t)b * BLOB_B + j * BLOB_J;
#pragma unroll
    for (int d = 0; d < DD; ++d) {
        float w_q = W0[d * C0 + j];
        float w_k = W0[(DD + d) * C0 + j];
        float w_d = W0[(2 * DD + d) * C0 + j];
        float w_p = W0[(3 * DD + d) * C0 + j];
        float qd = query[b * DD + d];
        dst[d] = w_k - w_d + qd * w_p;
        cj = fmaf(qd, w_q + w_d, cj);
    }
    dst[20] = cj;
}

// ---------------- pass 1: layer-1 pre-activation stats ----------------
// 8 channels per wave, weights VGPR-resident (PINNED), 64 pos/iteration.
__global__ __launch_bounds__(256, 2) void pass1_kernel(
    const float* __restrict__ keys, const float* __restrict__ blob,
    float* __restrict__ ws) {
    const int b = blockIdx.x >> 2, chunk = blockIdx.x & 3;
    const int tid = threadIdx.x, wave = tid >> 6, lane = tid & 63;
    const int j0 = wave * 8;
    const float* wb = blob + (size_t)b * BLOB_B;
    const float* kbase = keys + ((size_t)b * TT + chunk * (TT / 4)) * DD;

    float wM[8][DD], cj8[8];
#pragma unroll
    for (int jj = 0; jj < 8; ++jj) {
        load_krow(wb + (j0 + jj) * BLOB_J, wM[jj]);
        cj8[jj] = wb[(j0 + jj) * BLOB_J + 20];
    }
#pragma unroll
    for (int jj = 0; jj < 8; ++jj) {
        PIN(cj8[jj]);
#pragma unroll
        for (int d = 0; d < DD; ++d) PIN(wM[jj][d]);
    }

    float s[8], q[8];
#pragma unroll
    for (int v = 0; v < 8; ++v) { s[v] = 0.f; q[v] = 0.f; }

#pragma unroll 1
    for (int it = 0; it < (TT / 4) / 64; ++it) {
        float kk[DD];
        load_krow(kbase + (size_t)(it * 64 + lane) * DD, kk);
#pragma unroll
        for (int jj = 0; jj < 8; ++jj) {
            float h = cj8[jj];
#pragma unroll
            for (int d = 0; d < DD; ++d) h = fmaf(kk[d], wM[jj][d], h);
            s[jj] += h;
            q[jj] = fmaf(h, h, q[jj]);
        }
    }
    float mine = 0.f;
#pragma unroll
    for (int v = 0; v < 16; ++v) {
        float val = (v < 8) ? s[v] : q[v - 8];
#pragma unroll
        for (int o = 32; o >= 1; o >>= 1) val += __shfl_xor(val, o);
        if (lane == v) mine = val;
    }
    __shared__ float red[64];
    if (lane < 16) {
        int j = j0 + (lane & 7);
        red[(lane < 8 ? 0 : 32) + j] = mine;
    }
    __syncthreads();
    if (tid < 64) atomicAdd(&ws[WS_SUM0 + tid], red[tid]);
}

// ---------------- finalize: mean/var -> scale/shift ----------------
__global__ void finalize_kernel(float* __restrict__ ws, int nch, int sumOff,
                                int sqOff, int scOff, int shOff) {
    int j = threadIdx.x;
    if (j < nch) {
        const float invN = 1.0f / (float)(BB * TT);
        float mean = ws[sumOff + j] * invN;
        float ex2 = ws[sqOff + j] * invN;
        float var = ex2 - mean * mean;
        float sc = rsqrtf(var + 1e-9f);
        ws[scOff + j] = sc;
        ws[shOff + j] = -mean * sc;
    }
}

// Stage per-batch weights into LDS. lw row (24 floats, 96B):
// [0..19]=wM, [20]=c, [21]=sc0, [22]=sh0, [23]=al0  ([20..23] is one b128).
#define STAGE_WEIGHTS()                                                      \
    for (int idx = tid; idx < C0 * 24; idx += NTH) {                         \
        int j = idx / 24, r = idx - j * 24;                                  \
        float v;                                                             \
        if (r < 21) v = blob[(size_t)b * BLOB_B + j * BLOB_J + r];           \
        else if (r == 21) v = ws[WS_SCALE0 + j];                             \
        else if (r == 22) v = ws[WS_SHIFT0 + j];                             \
        else v = a0[j];                                                      \
        lw[idx] = v;                                                         \
    }                                                                        \
    for (int idx = tid; idx < C0 * C1; idx += NTH) lw1[idx] = W1[idx];

// Load NPOS key rows and PIN them (defeat rematerialization - R5 bug).
#define LOAD_AND_PIN_KEYS()                                                  \
    const float* kbase = keys + ((size_t)b * TT + chunk * POSB) * DD;        \
    float kk[NPOS][DD];                                                      \
    _Pragma("unroll") for (int pp = 0; pp < NPOS; ++pp)                      \
        load_krow(kbase + (size_t)(tid + pp * NTH) * DD, kk[pp]);            \
    _Pragma("unroll") for (int pp = 0; pp < NPOS; ++pp)                      \
        _Pragma("unroll") for (int d = 0; d < DD; ++d) PIN(kk[pp][d]);

// j-loop: per channel, 10 explicit ds_read_b128 of weights, apply to NPOS
// positions. h1[pp][c] accumulates layer-2 pre-activations (minus b1).
#define TOWER_JLOOP()                                                        \
    _Pragma("unroll 1") for (int j = 0; j < C0; ++j) {                       \
        const float4* wv = (const float4*)&lw[j * 24];                       \
        float4 A = wv[0], B = wv[1], Cc = wv[2], E = wv[3], F = wv[4],       \
               P = wv[5];                                                    \
        const float4* uv = (const float4*)&lw1[j * C1];                      \
        float4 U0 = uv[0], U1 = uv[1], U2 = uv[2], U3 = uv[3];               \
        float wr[DD] = {A.x,  A.y,  A.z,  A.w,  B.x,  B.y,  B.z,             \
                        B.w,  Cc.x, Cc.y, Cc.z, Cc.w, E.x,  E.y,             \
                        E.z,  E.w,  F.x,  F.y,  F.z,  F.w};                  \
        float ur[C1] = {U0.x, U0.y, U0.z, U0.w, U1.x, U1.y, U1.z, U1.w,      \
                        U2.x, U2.y, U2.z, U2.w, U3.x, U3.y, U3.z, U3.w};     \
        float h[NPOS];                                                       \
        _Pragma("unroll") for (int pp = 0; pp < NPOS; ++pp) {                \
            float hh = P.x;                                                  \
            _Pragma("unroll") for (int d = 0; d < DD; ++d)                   \
                hh = fmaf(kk[pp][d], wr[d], hh);                             \
            h[pp] = hh;                                                      \
        }                                                                    \
        _Pragma("unroll") for (int pp = 0; pp < NPOS; ++pp) {                \
            float pr = fast_sigmoid(fmaf(h[pp], P.y, P.z));                  \
            float h0d = h[pp] * (P.w + pr * (1.0f - P.w));                   \
            _Pragma("unroll") for (int c = 0; c < C1; ++c)                   \
                h1[pp][c] = fmaf(h0d, ur[c], h1[pp][c]);                     \
        }                                                                    \
    }

// ---------------- pass 2: layer-2 pre-activation stats ----------------
__global__ __launch_bounds__(NTH, 2) void pass2_kernel(
    const float* __restrict__ keys, const float* __restrict__ blob,
    const float* __restrict__ a0, const float* __restrict__ W1,
    const float* __restrict__ b1, float* __restrict__ ws) {
    const int b = blockIdx.x >> 1, chunk = blockIdx.x & 1;
    const int tid = threadIdx.x, wave = tid >> 6, lane = tid & 63;
    __shared__ float lw[C0 * 24];
    __shared__ float lw1[C0 * C1];
    __shared__ float red[4][32];
    STAGE_WEIGHTS()
    __syncthreads();

    LOAD_AND_PIN_KEYS()

    float h1[NPOS][C1];
#pragma unroll
    for (int pp = 0; pp < NPOS; ++pp)
#pragma unroll
        for (int c = 0; c < C1; ++c) h1[pp][c] = 0.f;

    TOWER_JLOOP()

    // add b1 (uniform s_load), accumulate thread-local stats
    float s1[C1], q1[C1];
#pragma unroll
    for (int c = 0; c < C1; ++c) {
        float bc = b1[c], sv = 0.f, qv = 0.f;
#pragma unroll
        for (int pp = 0; pp < NPOS; ++pp) {
            float v = h1[pp][c] + bc;
            sv += v;
            qv = fmaf(v, v, qv);
        }
        s1[c] = sv;
        q1[c] = qv;
    }
    // one butterfly at the very end
    float mine = 0.f;
#pragma unroll
    for (int v = 0; v < 32; ++v) {
        float val = (v < C1) ? s1[v] : q1[v - C1];
#pragma unroll
        for (int o = 32; o >= 1; o >>= 1) val += __shfl_xor(val, o);
        if (lane == v) mine = val;
    }
    if (lane < 32) red[wave][lane] = mine;
    __syncthreads();
    if (tid < 32)
        atomicAdd(&ws[WS_SUM1 + tid],
                  red[0][tid] + red[1][tid] + red[2][tid] + red[3][tid]);
}

// ---------------- pass 3: full tower + weighted key-sum ----------------
__global__ __launch_bounds__(NTH, 2) void pass3_kernel(
    const float* __restrict__ keys, const float* __restrict__ blob,
    const float* __restrict__ a0, const float* __restrict__ W1,
    const float* __restrict__ b1, const float* __restrict__ a1,
    const float* __restrict__ wk, const float* __restrict__ bk,
    const float* __restrict__ ws, float* __restrict__ out) {
    const int b = blockIdx.x >> 1, chunk = blockIdx.x & 1;
    const int tid = threadIdx.x, wave = tid >> 6, lane = tid & 63;
    __shared__ float lw[C0 * 24];
    __shared__ float lw1[C0 * C1];
    __shared__ float ld1[C1 * 4];  // sc1, sh1, al1, wk per layer-2 channel
    __shared__ float red[4][DD];
    STAGE_WEIGHTS()
    if (tid < C1) {
        ld1[tid * 4 + 0] = ws[WS_SCALE1 + tid];
        ld1[tid * 4 + 1] = ws[WS_SHIFT1 + tid];
        ld1[tid * 4 + 2] = a1[tid];
        ld1[tid * 4 + 3] = wk[tid];
    }
    __syncthreads();

    LOAD_AND_PIN_KEYS()

    float h1[NPOS][C1];
#pragma unroll
    for (int pp = 0; pp < NPOS; ++pp)
#pragma unroll
        for (int c = 0; c < C1; ++c) h1[pp][c] = 0.f;

    TOWER_JLOOP()

    // thread-local dice1 + score + weighted-key accumulation
    const float bkv = bk[0];
    float oacc[DD];
#pragma unroll
    for (int d = 0; d < DD; ++d) oacc[d] = 0.f;
#pragma unroll
    for (int pp = 0; pp < NPOS; ++pp) {
        float score = bkv;
#pragma unroll
        for (int c = 0; c < C1; ++c) {
            float v = h1[pp][c] + b1[c];
            float pr = fast_sigmoid(fmaf(v, ld1[c * 4 + 0], ld1[c * 4 + 1]));
            float al = ld1[c * 4 + 2];
            float hd = v * (al + pr * (1.0f - al));
            score = fmaf(hd, ld1[c * 4 + 3], score);
        }
#pragma unroll
        for (int d = 0; d < DD; ++d) oacc[d] = fmaf(score, kk[pp][d], oacc[d]);
    }
    // one butterfly at the very end
    float mine = 0.f;
#pragma unroll
    for (int v = 0; v < DD; ++v) {
        float val = oacc[v];
#pragma unroll
        for (int o = 32; o >= 1; o >>= 1) val += __shfl_xor(val, o);
        if (lane == v) mine = val;
    }
    if (lane < DD) red[wave][lane] = mine;
    __syncthreads();
    if (tid < DD)
        atomicAdd(&out[b * DD + tid],
                  red[0][tid] + red[1][tid] + red[2][tid] + red[3][tid]);
}

extern "C" void kernel_launch(void* const* d_in, const int* in_sizes, int n_in,
                              void* d_out, int out_size, void* d_ws,
                              size_t ws_size, hipStream_t stream) {
    const float* keys = (const float*)d_in[0];
    const float* query = (const float*)d_in[1];
    // d_in[2] = mask: intentionally unused
    const float* W0 = (const float*)d_in[3];
    const float* b0 = (const float*)d_in[4];
    const float* a0 = (const float*)d_in[5];
    const float* W1 = (const float*)d_in[6];
    const float* b1 = (const float*)d_in[7];
    const float* a1 = (const float*)d_in[8];
    const float* wk = (const float*)d_in[9];
    const float* bk = (const float*)d_in[10];
    float* out = (float*)d_out;
    float* ws = (float*)d_ws;
    float* blob = ws + WS_BLOB;  // 512*768 floats = 1.5 MB scratch

    hipMemsetAsync(ws, 0, 96 * sizeof(float), stream);  // sums area
    hipMemsetAsync(out, 0, (size_t)out_size * sizeof(float), stream);

    prep_kernel<<<BB / 2, 64, 0, stream>>>(query, W0, b0, blob);

    pass1_kernel<<<BB * 4, 256, 0, stream>>>(keys, blob, ws);
    finalize_kernel<<<1, 32, 0, stream>>>(ws, 32, WS_SUM0, WS_SQ0, WS_SCALE0,
                                          WS_SHIFT0);
    pass2_kernel<<<BB * NBLK, NTH, 0, stream>>>(keys, blob, a0, W1, b1, ws);
    finalize_kernel<<<1, 16, 0, stream>>>(ws, 16, WS_SUM1, WS_SQ1, WS_SCALE1,
                                          WS_SHIFT1);
    pass3_kernel<<<BB * NBLK, NTH, 0, stream>>>(keys, blob, a0, W1, b1, a1, wk,
                                                bk, ws, out);
}